// Round 1
// baseline (341.687 us; speedup 1.0000x reference)
//
#include <hip/hip_runtime.h>

typedef unsigned short u16;
typedef __attribute__((ext_vector_type(8))) __bf16 bf16x8;
typedef __attribute__((ext_vector_type(4))) float f32x4;

#define DEVI __device__ __forceinline__

DEVI u16 f2bf(float f) {
    unsigned u = __builtin_bit_cast(unsigned, f);
    u += 0x7fffu + ((u >> 16) & 1u);   // round-to-nearest-even
    return (u16)(u >> 16);
}

DEVI bf16x8 ldsf(const u16* p) { return *(const bf16x8*)p; }

DEVI f32x4 mfma16(bf16x8 a, bf16x8 b, f32x4 c) {
    return __builtin_amdgcn_mfma_f32_16x16x32_bf16(a, b, c, 0, 0, 0);
}

// ---------------- prep kernels ----------------

// x [B,T,1024] fp32 -> xbf [B,H,T,64] bf16
__global__ __launch_bounds__(256) void k_convert_x(const float* __restrict__ x, u16* __restrict__ xbf) {
    int i = blockIdx.x * 256 + threadIdx.x;      // 1,048,576 float4 groups
    float4 v = ((const float4*)x)[i];
    ushort4 o;
    o.x = f2bf(v.x); o.y = f2bf(v.y); o.z = f2bf(v.z); o.w = f2bf(v.w);
    int d4 = i & 15, h = (i >> 4) & 15, t = (i >> 8) & 2047, b = i >> 19;
    ((ushort4*)xbf)[((b * 16 + h) * 2048 + t) * 16 + d4] = o;
}

// MT[h][a][b] = sum_j Wq[h][b][j] * Wk[h][a][j] / 8   (= M^T, scaled), bf16
__global__ __launch_bounds__(256) void k_mt(const float* __restrict__ Wq, const float* __restrict__ Wk,
                                            u16* __restrict__ MT) {
    int idx = blockIdx.x * 256 + threadIdx.x;    // 65536
    int h = idx >> 12, a = (idx >> 6) & 63, b = idx & 63;
    const float4* q = (const float4*)(Wq + h * 65536 + b * 1024);
    const float4* k = (const float4*)(Wk + h * 65536 + a * 1024);
    float s0 = 0.f, s1 = 0.f, s2 = 0.f, s3 = 0.f;
#pragma unroll 8
    for (int j = 0; j < 256; j++) {
        float4 qq = q[j], kk = k[j];
        s0 += qq.x * kk.x; s1 += qq.y * kk.y; s2 += qq.z * kk.z; s3 += qq.w * kk.w;
    }
    MT[idx] = f2bf((s0 + s1 + s2 + s3) * 0.125f);
}

// Wv fp32 -> bf16 flat copy
__global__ __launch_bounds__(256) void k_wv(const float* __restrict__ Wv, u16* __restrict__ Wvbf) {
    int i = blockIdx.x * 256 + threadIdx.x;      // 262,144 float4 groups
    float4 v = ((const float4*)Wv)[i];
    ushort4 o;
    o.x = f2bf(v.x); o.y = f2bf(v.y); o.z = f2bf(v.z); o.w = f2bf(v.w);
    ((ushort4*)Wvbf)[i] = o;
}

// WoT[h][n][k] = Wo[h*1024+k][n], bf16 (transpose via LDS)
__global__ __launch_bounds__(256) void k_wot(const float* __restrict__ Wo, u16* __restrict__ WoT) {
    __shared__ float T[64][65];
    int h = blockIdx.z, n0 = blockIdx.x * 64, k0 = blockIdx.y * 64;
    int tid = threadIdx.x, row = tid >> 2, c = (tid & 3) * 16;
    const float* src = Wo + (h * 1024 + k0 + row) * 1024 + n0 + c;
#pragma unroll
    for (int j = 0; j < 16; j += 4) {
        float4 v = *(const float4*)(src + j);
        T[row][c + j] = v.x; T[row][c + j + 1] = v.y; T[row][c + j + 2] = v.z; T[row][c + j + 3] = v.w;
    }
    __syncthreads();
    u16* dst = WoT + h * 1048576 + (n0 + row) * 1024 + k0 + c;
#pragma unroll
    for (int j = 0; j < 16; j += 4) {
        ushort4 v;
        v.x = f2bf(T[c + j][row]); v.y = f2bf(T[c + j + 1][row]);
        v.z = f2bf(T[c + j + 2][row]); v.w = f2bf(T[c + j + 3][row]);
        *(ushort4*)(dst + j) = v;
    }
}

// WvoT[m][h*64+d] = sum_j Wvbf[h][d][j] * WoT[h][m][j], bf16 (64x64 tile MFMA GEMM)
__global__ __launch_bounds__(256) void k_wvo(const u16* __restrict__ Wvbf, const u16* __restrict__ WoT,
                                             u16* __restrict__ WvoT) {
    __shared__ __align__(16) u16 AL[4608], BL[4608];   // [64][72]
    int tid = threadIdx.x, w = tid >> 6, lane = tid & 63, g = lane >> 4, ln = lane & 15;
    int h = blockIdx.y, n0 = blockIdx.x * 64;
    f32x4 c[4] = {};
    int row = tid >> 2, c2 = (tid & 3) * 16;
    const u16* Abase = Wvbf + h * 65536 + row * 1024;
    const u16* Bbase = WoT + h * 1048576 + (n0 + row) * 1024;
    for (int kb = 0; kb < 16; kb++) {
        __syncthreads();
        *(uint4*)(AL + row * 72 + c2)     = *(const uint4*)(Abase + kb * 64 + c2);
        *(uint4*)(AL + row * 72 + c2 + 8) = *(const uint4*)(Abase + kb * 64 + c2 + 8);
        *(uint4*)(BL + row * 72 + c2)     = *(const uint4*)(Bbase + kb * 64 + c2);
        *(uint4*)(BL + row * 72 + c2 + 8) = *(const uint4*)(Bbase + kb * 64 + c2 + 8);
        __syncthreads();
#pragma unroll
        for (int ks = 0; ks < 2; ks++) {
            bf16x8 a = ldsf(AL + (w * 16 + ln) * 72 + ks * 32 + g * 8);
#pragma unroll
            for (int nt = 0; nt < 4; nt++) {
                bf16x8 bb = ldsf(BL + (nt * 16 + ln) * 72 + ks * 32 + g * 8);
                c[nt] = mfma16(a, bb, c[nt]);
            }
        }
    }
#pragma unroll
    for (int nt = 0; nt < 4; nt++) {
        ushort4 v;
        v.x = f2bf(c[nt][0]); v.y = f2bf(c[nt][1]); v.z = f2bf(c[nt][2]); v.w = f2bf(c[nt][3]);
        *(ushort4*)(WvoT + (n0 + nt * 16 + ln) * 1024 + h * 64 + w * 16 + g * 4) = v;
    }
}

// ---------------- flash attention ----------------
// per (b,h): Q' = xh * MT^T (on the fly), K = V = xh;  U[b][t][h*64+d] = softmax(Q' K^T) V
__global__ __launch_bounds__(256) void k_attn(const u16* __restrict__ xbf, const u16* __restrict__ MT,
                                              u16* __restrict__ U) {
    __shared__ __align__(16) u16 sm[4 * 4608];
    u16* QL  = sm;               // [64][72] Q' bf16
    u16* KL  = sm + 4608;        // [64][72] K tile (prologue: MT)
    u16* VtL = sm + 2 * 4608;    // [64][72] V^T tile (prologue: XQ)
    u16* PL  = sm + 3 * 4608;    // 4 waves x [16][72]

    const int tid = threadIdx.x;
    const int w = tid >> 6, lane = tid & 63, g = lane >> 4, ln = lane & 15;
    const int qt = blockIdx.x, h = blockIdx.y, b = blockIdx.z;
    const u16* xh = xbf + ((b * 16 + h) * 2048) * 64;   // [2048][64]

    {   // prologue staging: MT -> KL, XQ -> VtL
        int row = tid >> 2, c2 = (tid & 3) * 16;
        const u16* sm_src = MT + h * 4096 + row * 64 + c2;
        *(uint4*)(KL + row * 72 + c2)     = *(const uint4*)sm_src;
        *(uint4*)(KL + row * 72 + c2 + 8) = *(const uint4*)(sm_src + 8);
        const u16* sx = xh + (qt * 64 + row) * 64 + c2;
        *(uint4*)(VtL + row * 72 + c2)     = *(const uint4*)sx;
        *(uint4*)(VtL + row * 72 + c2 + 8) = *(const uint4*)(sx + 8);
    }
    __syncthreads();

    {   // Q' = XQ * M  (B-frag from MTL since MTL = M^T)
        f32x4 acc[4] = {};
#pragma unroll
        for (int ks = 0; ks < 2; ks++) {
            bf16x8 a = ldsf(VtL + (w * 16 + ln) * 72 + ks * 32 + g * 8);
#pragma unroll
            for (int nt = 0; nt < 4; nt++) {
                bf16x8 bb = ldsf(KL + (nt * 16 + ln) * 72 + ks * 32 + g * 8);
                acc[nt] = mfma16(a, bb, acc[nt]);
            }
        }
#pragma unroll
        for (int nt = 0; nt < 4; nt++)
#pragma unroll
            for (int r = 0; r < 4; r++)
                QL[(w * 16 + g * 4 + r) * 72 + nt * 16 + ln] = f2bf(acc[nt][r]);
    }
    __syncthreads();

    float mrow[4] = {-1e30f, -1e30f, -1e30f, -1e30f};
    float lrow[4] = {0.f, 0.f, 0.f, 0.f};
    f32x4 o[4] = {};

    for (int kt = 0; kt < 32; kt++) {
        {   // stage K tile (row-major) and V^T tile
            int row = tid >> 2, c2 = (tid & 3) * 16;
            const u16* sx = xh + (kt * 64 + row) * 64 + c2;
            *(uint4*)(KL + row * 72 + c2)     = *(const uint4*)sx;
            *(uint4*)(KL + row * 72 + c2 + 8) = *(const uint4*)(sx + 8);
            int d = tid & 63, rg = tid >> 6;
            const u16* sv = xh + (kt * 64 + rg * 16) * 64 + d;
            unsigned p0[4], p1[4];
#pragma unroll
            for (int j = 0; j < 4; j++)
                p0[j] = (unsigned)sv[(2 * j) * 64] | ((unsigned)sv[(2 * j + 1) * 64] << 16);
#pragma unroll
            for (int j = 0; j < 4; j++)
                p1[j] = (unsigned)sv[(8 + 2 * j) * 64] | ((unsigned)sv[(8 + 2 * j + 1) * 64] << 16);
            uint4 lo; lo.x = p0[0]; lo.y = p0[1]; lo.z = p0[2]; lo.w = p0[3];
            uint4 hi; hi.x = p1[0]; hi.y = p1[1]; hi.z = p1[2]; hi.w = p1[3];
            *(uint4*)(VtL + d * 72 + rg * 16)     = lo;
            *(uint4*)(VtL + d * 72 + rg * 16 + 8) = hi;
        }
        __syncthreads();

        // S = Q'(16 rows) * K^T (64 cols)
        f32x4 s[4] = {};
#pragma unroll
        for (int ks = 0; ks < 2; ks++) {
            bf16x8 a = ldsf(QL + (w * 16 + ln) * 72 + ks * 32 + g * 8);
#pragma unroll
            for (int nt = 0; nt < 4; nt++) {
                bf16x8 bb = ldsf(KL + (nt * 16 + ln) * 72 + ks * 32 + g * 8);
                s[nt] = mfma16(a, bb, s[nt]);
            }
        }

        // online softmax
        float alpha[4];
#pragma unroll
        for (int r = 0; r < 4; r++) {
            float m0 = fmaxf(fmaxf(s[0][r], s[1][r]), fmaxf(s[2][r], s[3][r]));
#pragma unroll
            for (int off = 1; off < 16; off <<= 1) m0 = fmaxf(m0, __shfl_xor(m0, off, 64));
            float mn = fmaxf(mrow[r], m0);
            alpha[r] = __expf(mrow[r] - mn);
            mrow[r] = mn;
        }
        float p[4][4];
#pragma unroll
        for (int nt = 0; nt < 4; nt++)
#pragma unroll
            for (int r = 0; r < 4; r++) p[nt][r] = __expf(s[nt][r] - mrow[r]);
#pragma unroll
        for (int r = 0; r < 4; r++) {
            float t = p[0][r] + p[1][r] + p[2][r] + p[3][r];
#pragma unroll
            for (int off = 1; off < 16; off <<= 1) t += __shfl_xor(t, off, 64);
            lrow[r] = lrow[r] * alpha[r] + t;
#pragma unroll
            for (int dt = 0; dt < 4; dt++) o[dt][r] *= alpha[r];
        }

        // P: C-layout -> LDS -> A-layout (verified m120 pattern)
        u16* PLw = PL + w * 1152;
#pragma unroll
        for (int nt = 0; nt < 4; nt++)
#pragma unroll
            for (int r = 0; r < 4; r++)
                PLw[(g * 4 + r) * 72 + nt * 16 + ln] = f2bf(p[nt][r]);
        asm volatile("s_waitcnt lgkmcnt(0)" ::: "memory");

        // O += P * V
#pragma unroll
        for (int ks = 0; ks < 2; ks++) {
            bf16x8 a = ldsf(PLw + ln * 72 + ks * 32 + g * 8);
#pragma unroll
            for (int dt = 0; dt < 4; dt++) {
                bf16x8 bb = ldsf(VtL + (dt * 16 + ln) * 72 + ks * 32 + g * 8);
                o[dt] = mfma16(a, bb, o[dt]);
            }
        }
        __syncthreads();
    }

    int tq = qt * 64 + w * 16 + g * 4;
#pragma unroll
    for (int r = 0; r < 4; r++) {
        float inv = 1.0f / lrow[r];
#pragma unroll
        for (int dt = 0; dt < 4; dt++)
            U[(b * 2048 + tq + r) * 1024 + h * 64 + dt * 16 + ln] = f2bf(o[dt][r] * inv);
    }
}

// out[r][n] = sum_k U[r][k] * WvoT[n][k] + bo[n], fp32
__global__ __launch_bounds__(256) void k_out(const u16* __restrict__ U, const u16* __restrict__ WvoT,
                                             const float* __restrict__ bo, float* __restrict__ out) {
    __shared__ __align__(16) u16 AL[4608], BL[4608];
    int tid = threadIdx.x, w = tid >> 6, lane = tid & 63, g = lane >> 4, ln = lane & 15;
    int n0 = blockIdx.x * 64, r0 = blockIdx.y * 64;
    f32x4 c[4] = {};
    int row = tid >> 2, c2 = (tid & 3) * 16;
    const u16* Abase = U + (r0 + row) * 1024;
    const u16* Bbase = WvoT + (n0 + row) * 1024;
    for (int kb = 0; kb < 16; kb++) {
        __syncthreads();
        *(uint4*)(AL + row * 72 + c2)     = *(const uint4*)(Abase + kb * 64 + c2);
        *(uint4*)(AL + row * 72 + c2 + 8) = *(const uint4*)(Abase + kb * 64 + c2 + 8);
        *(uint4*)(BL + row * 72 + c2)     = *(const uint4*)(Bbase + kb * 64 + c2);
        *(uint4*)(BL + row * 72 + c2 + 8) = *(const uint4*)(Bbase + kb * 64 + c2 + 8);
        __syncthreads();
#pragma unroll
        for (int ks = 0; ks < 2; ks++) {
            bf16x8 a = ldsf(AL + (w * 16 + ln) * 72 + ks * 32 + g * 8);
#pragma unroll
            for (int nt = 0; nt < 4; nt++) {
                bf16x8 bb = ldsf(BL + (nt * 16 + ln) * 72 + ks * 32 + g * 8);
                c[nt] = mfma16(a, bb, c[nt]);
            }
        }
    }
#pragma unroll
    for (int nt = 0; nt < 4; nt++) {
        int n = n0 + nt * 16 + ln;
        float bias = bo[n];
#pragma unroll
        for (int r = 0; r < 4; r++)
            out[(r0 + w * 16 + g * 4 + r) * 1024 + n] = c[nt][r] + bias;
    }
}

extern "C" void kernel_launch(void* const* d_in, const int* in_sizes, int n_in,
                              void* d_out, int out_size, void* d_ws, size_t ws_size,
                              hipStream_t stream) {
    const float* x  = (const float*)d_in[0];
    const float* Wq = (const float*)d_in[1];
    const float* Wk = (const float*)d_in[2];
    const float* Wv = (const float*)d_in[3];
    const float* Wo = (const float*)d_in[4];
    const float* bo = (const float*)d_in[5];
    float* out = (float*)d_out;

    char* ws = (char*)d_ws;
    u16* xbf  = (u16*)(ws);               //  8,388,608 B  [B,H,T,64]
    u16* MT   = (u16*)(ws + 8388608);     //    131,072 B  [H,64,64]
    u16* Wvbf = (u16*)(ws + 8519680);     //  2,097,152 B  [H,64,1024]
    u16* WoT  = (u16*)(ws + 10616832);    // 33,554,432 B  [H,1024,1024]
    u16* WvoT = (u16*)(ws + 44171264);    //  2,097,152 B  [1024,1024]
    u16* U    = (u16*)(ws + 46268416);    //  8,388,608 B  [B,T,1024]

    k_convert_x<<<4096, 256, 0, stream>>>(x, xbf);
    k_mt<<<256, 256, 0, stream>>>(Wq, Wk, MT);
    k_wv<<<1024, 256, 0, stream>>>(Wv, Wvbf);
    k_wot<<<dim3(16, 16, 16), 256, 0, stream>>>(Wo, WoT);
    k_wvo<<<dim3(16, 16), 256, 0, stream>>>(Wvbf, WoT, WvoT);
    k_attn<<<dim3(32, 16, 2), 256, 0, stream>>>(xbf, MT, U);
    k_out<<<dim3(16, 64), 256, 0, stream>>>(U, WvoT, bo, out);
}